// Round 4
// baseline (81.441 us; speedup 1.0000x reference)
//
#include <hip/hip_runtime.h>

#define NROWS 8192
#define NB    64               // 8192 / 128 row-blocks
#define NPAIR 2080             // NB*(NB+1)/2
#define NSEG  512              // k_main blocks; 32 segs of 5 tiles + 480 of 4
// ws layout: cnt[4] @0, partial[NSEG] @256, xn @16384
#define PART_OFF 256
#define XN_OFF   16384

typedef __bf16 bf16x8 __attribute__((ext_vector_type(8)));
typedef float  f32x4  __attribute__((ext_vector_type(4)));

__device__ __forceinline__ unsigned short f2bf(float f) {
  unsigned int u = __float_as_uint(f);
  u += 0x7fffu + ((u >> 16) & 1u);      // round-to-nearest-even
  return (unsigned short)(u >> 16);
}

__device__ __forceinline__ void gl_lds16(const void* g, void* l) {
  __builtin_amdgcn_global_load_lds(
      (const __attribute__((address_space(1))) unsigned int*)g,
      (__attribute__((address_space(3))) unsigned int*)l, 16, 0, 0);
}

// ---- row normalize + bf16 convert: 1 wave per row ----
__global__ __launch_bounds__(256) void k_norm(const float* __restrict__ x,
                                              unsigned short* __restrict__ xn) {
  int row  = blockIdx.x * 4 + (threadIdx.x >> 6);
  int lane = threadIdx.x & 63;
  float4 v = reinterpret_cast<const float4*>(x)[row * 64 + lane];
  float ss = v.x * v.x + v.y * v.y + v.z * v.z + v.w * v.w;
#pragma unroll
  for (int off = 32; off; off >>= 1) ss += __shfl_xor(ss, off);
  float inv = 1.0f / fmaxf(sqrtf(ss), 1e-8f);
  ushort4 o;
  o.x = f2bf(v.x * inv); o.y = f2bf(v.y * inv);
  o.z = f2bf(v.z * inv); o.w = f2bf(v.w * inv);
  reinterpret_cast<ushort4*>(xn)[row * 64 + lane] = o;
}

// ---- class histogram ----
__global__ __launch_bounds__(256) void k_hist(const int* __restrict__ t,
                                              int* __restrict__ cnt) {
  __shared__ int lc[4];
  if (threadIdx.x < 4) lc[threadIdx.x] = 0;
  __syncthreads();
  int i = blockIdx.x * 256 + threadIdx.x;
  atomicAdd(&lc[t[i]], 1);
  __syncthreads();
  if (threadIdx.x < 4) atomicAdd(&cnt[threadIdx.x], lc[threadIdx.x]);
}

// ---- strip-mined fused triangular GEMM-reduce ----
// Each block: 4-5 consecutive (r,cb) pairs. A-tile resident (64KB),
// B half-K chunks double-buffered (2x32KB). LDS layout k-chunk-major
// [ksub][128 rows][64B] with R2's verified zero-conflict swizzle
// key ((row>>1)&3)<<4 (row parity feeds bank bit 6 via the 64B stride).
__global__ __launch_bounds__(256, 1) void k_main(const unsigned short* __restrict__ xn,
                                                 const int* __restrict__ tgt,
                                                 const int* __restrict__ cnt,
                                                 float* __restrict__ partial) {
  __shared__ __align__(16) char lA[8 * 128 * 64];       // 64 KB: A full-K
  __shared__ __align__(16) char lB[2][4 * 128 * 64];    // 2 x 32 KB: B half-K dbuf
  __shared__ float lW[16];
  __shared__ int   lsL;
  __shared__ float wred[4];

  // XCD-aware bijective swizzle (512 = 8*64)
  int b0 = blockIdx.x;
  int s  = (b0 & 7) * (NSEG / 8) + (b0 >> 3);
  // segment -> pair range: 5 tiles when s%16==0 (32 such), else 4
  int nlong_before = (s + 15) >> 4;          // # of long segs with index < s
  int start = 4 * s + nlong_before;
  int n     = 4 + ((s & 15) == 0 ? 1 : 0);
  // decode start -> (r, cb)
  int r = 0, rem = start;
  while (rem >= NB - r) { rem -= NB - r; ++r; }
  int cb = r + rem;

  const int tid = threadIdx.x, wave = tid >> 6, lane = tid & 63;
  const char* xb = (const char*)xn;

  // stage A-tile for row-block rr: 64 insts (16/wave), each 1KB = 16 rows x 64B
  auto stageA = [&](int rr) {
    const char* src = xb + (size_t)rr * 128 * 512;
    int slot = (lane & 3) * 16;
#pragma unroll
    for (int it = 0; it < 16; ++it) {
      int g = it * 4 + wave;                 // wave-uniform
      int ksub = g >> 3, rbase = (g & 7) * 16;
      int row  = rbase + (lane >> 2);
      int key  = ((row >> 1) & 3) << 4;
      gl_lds16(src + (size_t)row * 512 + ksub * 64 + (slot ^ key),
               &lA[ksub * 8192 + rbase * 64]);
    }
  };
  // stage B half-K chunk h of col-block cc: 32 insts (8/wave)
  auto stageB = [&](int buf, int cc, int h) {
    const char* src = xb + (size_t)cc * 128 * 512 + h * 256;
    int slot = (lane & 3) * 16;
#pragma unroll
    for (int it = 0; it < 8; ++it) {
      int g = it * 4 + wave;                 // wave-uniform
      int ksub = g >> 3, rbase = (g & 7) * 16;
      int row  = rbase + (lane >> 2);
      int key  = ((row >> 1) & 3) << 4;
      gl_lds16(src + (size_t)row * 512 + ksub * 64 + (slot ^ key),
               &lB[buf][ksub * 8192 + rbase * 64]);
    }
  };

  const int wr = (wave >> 1) * 64, wc = (wave & 1) * 64;
  const int l15 = lane & 15;
  const int q16 = (lane >> 4) << 4;
  const int rowj = (lane >> 4) * 4;

  // one half-K (4 k-steps, 64 MFMA/wave) from buf, half h
  auto compute = [&](int buf, int h, f32x4 (&acc)[4][4]) {
    const char* cB = lB[buf];
#pragma unroll
    for (int ks = 0; ks < 4; ++ks) {
      bf16x8 af[4], bfr[4];
      int ksA = h * 4 + ks;
#pragma unroll
      for (int m = 0; m < 4; ++m) {
        int a = wr + m * 16 + l15;
        af[m] = *(const bf16x8*)(lA + ksA * 8192 + a * 64 + (q16 ^ (((a >> 1) & 3) << 4)));
      }
#pragma unroll
      for (int nn = 0; nn < 4; ++nn) {
        int b = wc + nn * 16 + l15;
        bfr[nn] = *(const bf16x8*)(cB + ks * 8192 + b * 64 + (q16 ^ (((b >> 1) & 3) << 4)));
      }
#pragma unroll
      for (int m = 0; m < 4; ++m)
#pragma unroll
        for (int nn = 0; nn < 4; ++nn)
          acc[m][nn] = __builtin_amdgcn_mfma_f32_16x16x32_bf16(af[m], bfr[nn], acc[m][nn], 0, 0, 0);
    }
  };

  // prologue: A + first B chunk + tables, one drain barrier
  stageA(r);
  stageB(0, cb, 0);
  if (tid < 16) {
    int ta = tid >> 2, tb = tid & 3;
    float w = 0.0f;
#pragma unroll
    for (int i = 0; i < 4; ++i) {
      int ci = cnt[i];
      if (ci > 0 && ((ta == i) == (tb == i))) w += 1.0f / (float)ci;
    }
    lW[tid] = w;
  }
  if (tid == 0) {
    int L = -1;
    for (int i = 0; i < 4; ++i) if (cnt[i] > 0) L = i;
    lsL = L;
  }
  __syncthreads();
  const int L = lsL;

  float lsum = 0.0f;
  int cur = 0;
  for (int i = 0; i < n; ++i) {
    f32x4 acc[4][4];
#pragma unroll
    for (int m = 0; m < 4; ++m)
#pragma unroll
      for (int nn = 0; nn < 4; ++nn)
        acc[m][nn] = (f32x4){0.f, 0.f, 0.f, 0.f};

    // chunk 0 (k 0..127): prefetch this tile's chunk 1 first
    stageB(cur ^ 1, cb, 1);
    compute(cur, 0, acc);
    __syncthreads();
    cur ^= 1;

    // chunk 1 (k 128..255): prefetch next tile's chunk 0 if same row
    int ncb = cb + 1, nr = r, nrow = 0;
    if (ncb == NB) { nr = r + 1; ncb = nr; nrow = 1; }
    int have = (i + 1 < n);
    if (have && !nrow) stageB(cur ^ 1, ncb, 0);
    compute(cur, 1, acc);
    __syncthreads();
    cur ^= 1;

    // epilogue for tile (r, cb): targets read straight from global (L2-hit)
    {
      const int rg = r * 128 + wr;
      const int cg = cb * 128 + wc;
      int tb[4], tbl[4];
#pragma unroll
      for (int nn = 0; nn < 4; ++nn) {
        tb[nn] = tgt[cg + nn * 16 + l15];
        tbl[nn] = (tb[nn] == L);
      }
#pragma unroll
      for (int m = 0; m < 4; ++m) {
#pragma unroll
        for (int j = 0; j < 4; ++j) {
          int ar = m * 16 + rowj + j;
          int ta = tgt[rg + ar];
          int tal = (ta == L);
          int ga = rg + ar;
#pragma unroll
          for (int nn = 0; nn < 4; ++nn) {
            int gb = cg + nn * 16 + l15;
            if (ga < gb) {
              float cv = acc[m][nn][j];
              float contrib = lW[ta * 4 + tb[nn]] * (1.0f - cv);
              if (tal != tbl[nn]) contrib += fmaxf(cv - 0.5f, 0.0f);
              lsum += contrib;
            }
          }
        }
      }
    }

    // row change: restage A + next B chunk0, drain (rare: <=1-2 per block)
    if (have && nrow) {
      stageA(nr);
      stageB(cur, ncb, 0);
      __syncthreads();
    }
    cb = ncb; r = nr;
  }

#pragma unroll
  for (int off = 32; off; off >>= 1) lsum += __shfl_xor(lsum, off);
  if (lane == 0) wred[wave] = lsum;
  __syncthreads();
  if (tid == 0) partial[s] = wred[0] + wred[1] + wred[2] + wred[3];
}

// ---- final reduce: 512 partials -> scalar ----
__global__ __launch_bounds__(256) void k_reduce(const float* __restrict__ partial,
                                                float* __restrict__ out) {
  __shared__ float red[4];
  int tid = threadIdx.x, wave = tid >> 6, lane = tid & 63;
  float s = partial[tid] + partial[tid + 256];
#pragma unroll
  for (int off = 32; off; off >>= 1) s += __shfl_xor(s, off);
  if (lane == 0) red[wave] = s;
  __syncthreads();
  if (tid == 0) out[0] = (red[0] + red[1] + red[2] + red[3]) * (1.0f / 8192.0f);
}

extern "C" void kernel_launch(void* const* d_in, const int* in_sizes, int n_in,
                              void* d_out, int out_size, void* d_ws, size_t ws_size,
                              hipStream_t stream) {
  (void)in_sizes; (void)n_in; (void)out_size; (void)ws_size;
  const float* x  = (const float*)d_in[0];
  const int* tgt  = (const int*)d_in[1];
  float* out      = (float*)d_out;
  int* cnt        = (int*)d_ws;
  float* partial  = (float*)((char*)d_ws + PART_OFF);
  unsigned short* xn = (unsigned short*)((char*)d_ws + XN_OFF);

  hipMemsetAsync(cnt, 0, 4 * sizeof(int), stream);
  k_norm<<<NROWS / 4, 256, 0, stream>>>(x, xn);
  k_hist<<<NROWS / 256, 256, 0, stream>>>(tgt, cnt);
  k_main<<<NSEG, 256, 0, stream>>>(xn, tgt, cnt, partial);
  k_reduce<<<1, 256, 0, stream>>>(partial, out);
}

// Round 5
// 80.612 us; speedup vs baseline: 1.0103x; 1.0103x over previous
//
#include <hip/hip_runtime.h>

#define NROWS 8192
// ws layout (bytes):
#define CNT_OFF   0        // int cnt[4]
#define CTR_OFF   16       // int ctr[2]: [0]=#non-L, [1]=#L
#define P2_OFF    64       // float partial2[1024]
#define INV_OFF   4608     // float inv[8192]
#define IDXNL_OFF 37376    // u16[8192]
#define IDXL_OFF  53760    // u16[8192]
#define S1_OFF    70144    // float sums1[32][1056]
#define XN_OFF    262144   // bf16 xn[8192][256]
#define S1STRIDE  1056

typedef __bf16 bf16x8 __attribute__((ext_vector_type(8)));
typedef float  f32x4  __attribute__((ext_vector_type(4)));

__device__ __forceinline__ unsigned short f2bf(float f) {
  unsigned int u = __float_as_uint(f);
  u += 0x7fffu + ((u >> 16) & 1u);
  return (unsigned short)(u >> 16);
}

__device__ __forceinline__ void gl_lds16(const void* g, void* l) {
  __builtin_amdgcn_global_load_lds(
      (const __attribute__((address_space(1))) unsigned int*)g,
      (__attribute__((address_space(3))) unsigned int*)l, 16, 0, 0);
}

// ---- normalize + bf16 + inv + histogram: 128 blocks x 1024 thr, 64 rows each ----
__global__ __launch_bounds__(1024) void k_normhist(const float* __restrict__ x,
                                                   const int* __restrict__ tgt,
                                                   unsigned short* __restrict__ xn,
                                                   float* __restrict__ inv,
                                                   int* __restrict__ cnt) {
  __shared__ int lh[4];
  const int tid = threadIdx.x, w = tid >> 6, lane = tid & 63;
  if (tid < 4) lh[tid] = 0;
#pragma unroll
  for (int i = 0; i < 4; ++i) {
    int row = blockIdx.x * 64 + w * 4 + i;
    float4 v = reinterpret_cast<const float4*>(x)[row * 64 + lane];
    float ss = v.x * v.x + v.y * v.y + v.z * v.z + v.w * v.w;
#pragma unroll
    for (int off = 32; off; off >>= 1) ss += __shfl_xor(ss, off);
    float iv = 1.0f / fmaxf(sqrtf(ss), 1e-8f);
    if (lane == 0) inv[row] = iv;
    ushort4 o;
    o.x = f2bf(v.x * iv); o.y = f2bf(v.y * iv);
    o.z = f2bf(v.z * iv); o.w = f2bf(v.w * iv);
    reinterpret_cast<ushort4*>(xn)[row * 64 + lane] = o;
  }
  __syncthreads();
  if (tid < 64) atomicAdd(&lh[tgt[blockIdx.x * 64 + tid]], 1);
  __syncthreads();
  if (tid < 4) atomicAdd(&cnt[tid], lh[tid]);
}

// ---- partition rows by class-L + class-sum partials: 32 blocks x 256 ----
__global__ __launch_bounds__(256) void k_cls(const float* __restrict__ x,
                                             const float* __restrict__ inv,
                                             const int* __restrict__ tgt,
                                             const int* __restrict__ cnt,
                                             int* __restrict__ ctr,
                                             unsigned short* __restrict__ idxNL,
                                             unsigned short* __restrict__ idxL,
                                             float* __restrict__ sums1) {
  __shared__ float sred[4];
  const int tid = threadIdx.x, lane = tid & 63, wv = tid >> 6;
  int L = 0;
#pragma unroll
  for (int i = 0; i < 4; ++i) if (cnt[i] > 0) L = i;

  // partition: wave-aggregated atomics
  {
    int r = blockIdx.x * 256 + tid;
    bool isL = (tgt[r] == L);
    unsigned long long mk = __ballot(isL);
    int pos = __popcll(mk & ((1ull << lane) - 1ull));
    int nl = __popcll(mk);
    int baseL = 0, baseN = 0;
    if (lane == 0) {
      baseL = atomicAdd(&ctr[1], nl);
      baseN = atomicAdd(&ctr[0], 64 - nl);
    }
    baseL = __shfl(baseL, 0);
    baseN = __shfl(baseN, 0);
    if (isL) idxL[baseL + pos] = (unsigned short)r;
    else     idxNL[baseN + (lane - pos)] = (unsigned short)r;
  }

  // class sums: thread d over 256 rows
  float m0 = 0, m1 = 0, m2 = 0, m3 = 0, dacc = 0;
  int r0 = blockIdx.x * 256;
  for (int i = 0; i < 256; ++i) {
    int r = r0 + i;
    float v = x[(size_t)r * 256 + tid] * inv[r];
    int c = tgt[r];
    m0 += (c == 0) ? v : 0.0f;
    m1 += (c == 1) ? v : 0.0f;
    m2 += (c == 2) ? v : 0.0f;
    m3 += (c == 3) ? v : 0.0f;
    dacc += v * v;
  }
  float* p = sums1 + blockIdx.x * S1STRIDE;
  p[tid] = m0; p[256 + tid] = m1; p[512 + tid] = m2; p[768 + tid] = m3;
#pragma unroll
  for (int off = 32; off; off >>= 1) dacc += __shfl_xor(dacc, off);
  if (lane == 0) sred[wv] = dacc;
  __syncthreads();
  if (tid == 0) p[1024] = sred[0] + sred[1] + sred[2] + sred[3];
}

// ---- rectangle GEMM-reduce: sum relu(c-0.5) over (non-L rows) x (L rows) ----
// 256^2 tile, 8 waves, 4 BK=64 chunks, 2 buffers, counted vmcnt
__global__ __launch_bounds__(512, 1) void k_main(const char* __restrict__ xnb,
                                                 const unsigned short* __restrict__ idxNL,
                                                 const unsigned short* __restrict__ idxL,
                                                 const int* __restrict__ ctr,
                                                 float* __restrict__ partial) {
  __shared__ char lds[2][65536];     // [buf][A 32KB | B 32KB]
  __shared__ float wred[8];

  const int tid = threadIdx.x;
  const int w = tid >> 6, l = tid & 63;
  const int bi = blockIdx.x >> 5, bj = blockIdx.x & 31;
  const int M = ctr[0], NL = ctr[1];

  if (bi * 256 >= M || bj * 256 >= NL) {
    if (tid == 0) partial[blockIdx.x] = 0.0f;
    return;
  }
  const int rm = min(256, M - bi * 256);
  const int rn = min(256, NL - bj * 256);
  const bool full = (rm == 256) && (rn == 256);

  // staged rows for this thread: row(j) = 8w + (l>>3) + 64j, part = l&7
  const int rsub = (w << 3) + (l >> 3);
  const unsigned pe = ((unsigned)((l & 7) ^ (l >> 3))) << 4;   // swizzled 16B slot
  unsigned aoff[4], boff[4];
#pragma unroll
  for (int j = 0; j < 4; ++j) {
    int rr = rsub + 64 * j;
    int ga = idxNL[bi * 256 + min(rr, rm - 1)];
    int gb = idxL [bj * 256 + min(rr, rn - 1)];
    aoff[j] = (unsigned)ga * 512u + pe;
    boff[j] = (unsigned)gb * 512u + pe;
  }

  auto stage = [&](int buf, int ch) {
    char* dA = &lds[buf][(w << 10)];
    char* dB = &lds[buf][32768 + (w << 10)];
    unsigned cbo = (unsigned)(ch << 7);
#pragma unroll
    for (int j = 0; j < 4; ++j)
      gl_lds16(xnb + (size_t)(aoff[j] + cbo), dA + (j << 13));
#pragma unroll
    for (int j = 0; j < 4; ++j)
      gl_lds16(xnb + (size_t)(boff[j] + cbo), dB + (j << 13));
  };

  const int wr = (w >> 2) * 128, wc = (w & 3) * 64;
  const int l15 = l & 15;
  const unsigned q16 = ((unsigned)(l >> 4)) << 4;
  const unsigned key = ((unsigned)(l & 7)) << 4;

  f32x4 acc[8][4];
#pragma unroll
  for (int m = 0; m < 8; ++m)
#pragma unroll
    for (int n = 0; n < 4; ++n)
      acc[m][n] = (f32x4){0.f, 0.f, 0.f, 0.f};

  auto compute = [&](int buf) {
    const char* bA = lds[buf];
    const char* bB = lds[buf] + 32768;
#pragma unroll
    for (int ks = 0; ks < 2; ++ks) {
      const unsigned q = (unsigned)(ks * 64) + q16;
      bf16x8 af[8], bfr[4];
#pragma unroll
      for (int m = 0; m < 8; ++m)
        af[m] = *(const bf16x8*)(bA + (wr + m * 16 + l15) * 128 + (q ^ key));
#pragma unroll
      for (int n = 0; n < 4; ++n)
        bfr[n] = *(const bf16x8*)(bB + (wc + n * 16 + l15) * 128 + (q ^ key));
#pragma unroll
      for (int m = 0; m < 8; ++m)
#pragma unroll
        for (int n = 0; n < 4; ++n)
          acc[m][n] = __builtin_amdgcn_mfma_f32_16x16x32_bf16(af[m], bfr[n], acc[m][n], 0, 0, 0);
    }
  };

  // counted-vmcnt pipeline: 8 loads/thread/chunk, never drain to 0 mid-loop
  stage(0, 0); stage(1, 1);
  asm volatile("s_waitcnt vmcnt(8)" ::: "memory");
  __builtin_amdgcn_s_barrier();
  compute(0);
  __builtin_amdgcn_s_barrier();
  stage(0, 2);
  asm volatile("s_waitcnt vmcnt(8)" ::: "memory");
  __builtin_amdgcn_s_barrier();
  compute(1);
  __builtin_amdgcn_s_barrier();
  stage(1, 3);
  asm volatile("s_waitcnt vmcnt(8)" ::: "memory");
  __builtin_amdgcn_s_barrier();
  compute(0);
  __builtin_amdgcn_s_barrier();
  asm volatile("s_waitcnt vmcnt(0)" ::: "memory");
  __builtin_amdgcn_s_barrier();
  compute(1);

  // epilogue: sum relu(c - 0.5); C/D layout col=lane&15, row=(lane>>4)*4+reg
  const int rowj = (l >> 4) * 4;
  float ls = 0.0f;
  if (full) {
#pragma unroll
    for (int m = 0; m < 8; ++m)
#pragma unroll
      for (int n = 0; n < 4; ++n)
#pragma unroll
        for (int j = 0; j < 4; ++j)
          ls += fmaxf(acc[m][n][j] - 0.5f, 0.0f);
  } else {
#pragma unroll
    for (int m = 0; m < 8; ++m) {
#pragma unroll
      for (int j = 0; j < 4; ++j) {
        bool rv = (wr + m * 16 + rowj + j) < rm;
#pragma unroll
        for (int n = 0; n < 4; ++n) {
          bool cv = (wc + n * 16 + l15) < rn;
          float g = fmaxf(acc[m][n][j] - 0.5f, 0.0f);
          ls += (rv && cv) ? g : 0.0f;
        }
      }
    }
  }
#pragma unroll
  for (int off = 32; off; off >>= 1) ls += __shfl_xor(ls, off);
  if (l == 0) wred[w] = ls;
  __syncthreads();
  if (tid == 0) {
    float s = 0.0f;
#pragma unroll
    for (int i = 0; i < 8; ++i) s += wred[i];
    partial[blockIdx.x] = s;
  }
}

// ---- final: closed-form same-class term + diff partials -> out ----
__global__ __launch_bounds__(256) void k_final(const float* __restrict__ sums1,
                                               const int* __restrict__ cnt,
                                               const int* __restrict__ ctr,
                                               const float* __restrict__ partial2,
                                               float* __restrict__ out) {
  __shared__ float sred[4];
  __shared__ float acc9[9];
  const int tid = threadIdx.x, wv = tid >> 6, lane = tid & 63;

  float m0 = 0, m1 = 0, m2 = 0, m3 = 0;
  for (int b = 0; b < 32; ++b) {
    const float* p = sums1 + b * S1STRIDE;
    m0 += p[tid]; m1 += p[256 + tid]; m2 += p[512 + tid]; m3 += p[768 + tid];
  }
  float T = m0 + m1 + m2 + m3;
  float vals[9];
  vals[0] = m0 * m0; vals[1] = m1 * m1; vals[2] = m2 * m2; vals[3] = m3 * m3;
  vals[4] = (T - m0) * (T - m0); vals[5] = (T - m1) * (T - m1);
  vals[6] = (T - m2) * (T - m2); vals[7] = (T - m3) * (T - m3);
  vals[8] = (tid < 32) ? sums1[tid * S1STRIDE + 1024] : 0.0f;
#pragma unroll
  for (int v = 0; v < 9; ++v) {
    float s = vals[v];
#pragma unroll
    for (int off = 32; off; off >>= 1) s += __shfl_xor(s, off);
    if (lane == 0) sred[wv] = s;
    __syncthreads();
    if (tid == 0) acc9[v] = sred[0] + sred[1] + sred[2] + sred[3];
    __syncthreads();
  }
  // diff partial sum
  float s = partial2[tid] + partial2[tid + 256] + partial2[tid + 512] + partial2[tid + 768];
#pragma unroll
  for (int off = 32; off; off >>= 1) s += __shfl_xor(s, off);
  if (lane == 0) sred[wv] = s;
  __syncthreads();
  if (tid == 0) {
    double dsum = (double)sred[0] + sred[1] + sred[2] + sred[3];
    double D = acc9[8];
    double same = 0.0;
#pragma unroll
    for (int i = 0; i < 4; ++i) {
      int k = cnt[i];
      if (k > 0) {
        double Pi = 0.5 * (double)k * (double)(k - 1)
                  + 0.5 * (double)(NROWS - k) * (double)(NROWS - k - 1);
        double Si = 0.5 * ((double)acc9[i] + (double)acc9[4 + i] - D);
        same += (Pi - Si) / (double)k;
      }
    }
    out[0] = (float)((same + dsum) / (double)NROWS);
  }
}

extern "C" void kernel_launch(void* const* d_in, const int* in_sizes, int n_in,
                              void* d_out, int out_size, void* d_ws, size_t ws_size,
                              hipStream_t stream) {
  (void)in_sizes; (void)n_in; (void)out_size; (void)ws_size;
  const float* x  = (const float*)d_in[0];
  const int* tgt  = (const int*)d_in[1];
  float* out      = (float*)d_out;
  char* ws        = (char*)d_ws;

  int* cnt        = (int*)(ws + CNT_OFF);
  int* ctr        = (int*)(ws + CTR_OFF);
  float* partial2 = (float*)(ws + P2_OFF);
  float* inv      = (float*)(ws + INV_OFF);
  unsigned short* idxNL = (unsigned short*)(ws + IDXNL_OFF);
  unsigned short* idxL  = (unsigned short*)(ws + IDXL_OFF);
  float* sums1    = (float*)(ws + S1_OFF);
  unsigned short* xn = (unsigned short*)(ws + XN_OFF);

  hipMemsetAsync(ws, 0, 32, stream);   // cnt + ctr
  k_normhist<<<128, 1024, 0, stream>>>(x, tgt, xn, inv, cnt);
  k_cls<<<32, 256, 0, stream>>>(x, inv, tgt, cnt, ctr, idxNL, idxL, sums1);
  k_main<<<1024, 512, 0, stream>>>((const char*)xn, idxNL, idxL, ctr, partial2);
  k_final<<<1, 256, 0, stream>>>(sums1, cnt, ctr, partial2, out);
}

// Round 6
// 69.733 us; speedup vs baseline: 1.1679x; 1.1560x over previous
//
#include <hip/hip_runtime.h>

#define NROWS 8192
// ws layout (bytes) — NOTHING requires pre-zeroed workspace
#define CNT_OFF   0         // int cnt[4]        (written by k_part)
#define CTR_OFF   16        // int ctr[2]        (written by k_part)
#define P2_OFF    64        // float partial2[256] (all written by k_main)
#define H_OFF     1152      // int h[128][4]     (written by k_normcs)
#define IDXNL_OFF 3328      // u16[8192]
#define IDXL_OFF  19712     // u16[8192]
#define CS_OFF    36864     // float cs[128][4][256] (512 KB)
#define XN_OFF    1048576   // bf16 xn[8192][256] (4 MB)

typedef __bf16 bf16x8 __attribute__((ext_vector_type(8)));
typedef float  f32x4  __attribute__((ext_vector_type(4)));

__device__ __forceinline__ unsigned short f2bf(float f) {
  unsigned int u = __float_as_uint(f);
  u += 0x7fffu + ((u >> 16) & 1u);
  return (unsigned short)(u >> 16);
}

__device__ __forceinline__ void gl_lds16(const void* g, void* l) {
  __builtin_amdgcn_global_load_lds(
      (const __attribute__((address_space(1))) unsigned int*)g,
      (__attribute__((address_space(3))) unsigned int*)l, 16, 0, 0);
}

// ---- normalize + bf16 + per-block class hist + per-block class column-sums ----
// 128 blocks x 1024 threads, 64 rows/block; wave w handles rows w*4..w*4+3 (all 64 lanes on one row)
__global__ __launch_bounds__(1024) void k_normcs(const float* __restrict__ x,
                                                 const int* __restrict__ tgt,
                                                 unsigned short* __restrict__ xn,
                                                 int* __restrict__ h,
                                                 float* __restrict__ cs) {
  __shared__ float lw[4][256];
  __shared__ int lh[4];
  const int tid = threadIdx.x, w = tid >> 6, lane = tid & 63;
  lw[tid >> 8][tid & 255] = 0.0f;
  if (tid < 4) lh[tid] = 0;
  __syncthreads();
  const int b = blockIdx.x;
#pragma unroll
  for (int i = 0; i < 4; ++i) {
    int row = b * 64 + w * 4 + i;
    float4 v = reinterpret_cast<const float4*>(x)[row * 64 + lane];
    float ss = v.x * v.x + v.y * v.y + v.z * v.z + v.w * v.w;
#pragma unroll
    for (int off = 32; off; off >>= 1) ss += __shfl_xor(ss, off);
    float iv = 1.0f / fmaxf(sqrtf(ss), 1e-8f);
    ushort4 o;
    o.x = f2bf(v.x * iv); o.y = f2bf(v.y * iv);
    o.z = f2bf(v.z * iv); o.w = f2bf(v.w * iv);
    reinterpret_cast<ushort4*>(xn)[row * 64 + lane] = o;
    int c = tgt[row];
    atomicAdd(&lw[c][lane * 4 + 0], v.x * iv);
    atomicAdd(&lw[c][lane * 4 + 1], v.y * iv);
    atomicAdd(&lw[c][lane * 4 + 2], v.z * iv);
    atomicAdd(&lw[c][lane * 4 + 3], v.w * iv);
    if (lane == 0) atomicAdd(&lh[c], 1);
  }
  __syncthreads();
  cs[b * 1024 + tid] = lw[tid >> 8][tid & 255];
  if (tid < 4) h[b * 4 + tid] = lh[tid];
}

// ---- partition rows into (non-L, L) lists; no atomics on global ----
__global__ __launch_bounds__(256) void k_part(const int* __restrict__ tgt,
                                              const int* __restrict__ h,
                                              int* __restrict__ cnt,
                                              int* __restrict__ ctr,
                                              unsigned short* __restrict__ idxNL,
                                              unsigned short* __restrict__ idxL) {
  __shared__ int lcnt[4], lnb, lwc[4];
  const int tid = threadIdx.x, w = tid >> 6, lane = tid & 63;
  if (tid < 4) lcnt[tid] = 0;
  if (tid == 0) lnb = 0;
  __syncthreads();
  if (tid < 128) {
    int4 hv = ((const int4*)h)[tid];
    atomicAdd(&lcnt[0], hv.x); atomicAdd(&lcnt[1], hv.y);
    atomicAdd(&lcnt[2], hv.z); atomicAdd(&lcnt[3], hv.w);
  }
  __syncthreads();
  int L = 0;
#pragma unroll
  for (int i = 0; i < 4; ++i) if (lcnt[i] > 0) L = i;
  // # of L-rows before this block's 256 rows (4 h-chunks of 64 per block)
  if (tid < 4 * blockIdx.x) atomicAdd(&lnb, h[tid * 4 + L]);
  int r = blockIdx.x * 256 + tid;
  bool isL = (tgt[r] == L);
  unsigned long long mk = __ballot(isL);
  int nl = __popcll(mk);
  if (lane == 0) lwc[w] = nl;
  __syncthreads();
  int baseL = lnb, baseN = blockIdx.x * 256 - lnb;
  for (int w2 = 0; w2 < w; ++w2) { baseL += lwc[w2]; baseN += 64 - lwc[w2]; }
  int pos = __popcll(mk & ((1ull << lane) - 1ull));
  if (isL) idxL[baseL + pos] = (unsigned short)r;
  else     idxNL[baseN + (lane - pos)] = (unsigned short)r;
  if (blockIdx.x == 0 && tid < 4) cnt[tid] = lcnt[tid];
  if (blockIdx.x == 0 && tid == 0) { ctr[1] = lcnt[L]; ctr[0] = NROWS - lcnt[L]; }
}

// ---- rectangle GEMM-reduce: sum relu(c-0.5) over (non-L) x (L) ----
// persistent 256 blocks x 512 thr; 256^2 tiles, 4 BK=64 chunks, 2 bufs, counted vmcnt
__global__ __launch_bounds__(512, 1) void k_main(const char* __restrict__ xnb,
                                                 const unsigned short* __restrict__ idxNL,
                                                 const unsigned short* __restrict__ idxL,
                                                 const int* __restrict__ ctr,
                                                 float* __restrict__ partial) {
  __shared__ char lds[2][65536];     // [buf][A 32KB | B 32KB]
  __shared__ float wred[8];

  const int tid = threadIdx.x;
  const int w = tid >> 6, l = tid & 63;
  const int M = ctr[0], NL = ctr[1];
  const int ni = (M + 255) >> 8, nj = (NL + 255) >> 8;
  const int ntiles = ni * nj;

  const int rsub = (w << 3) + (l >> 3);
  const unsigned pe = ((unsigned)((l & 7) ^ ((l >> 3) & 7))) << 4;
  const int wr = (w >> 2) * 128, wc = (w & 3) * 64;
  const int l15 = l & 15;
  const unsigned q16 = ((unsigned)(l >> 4)) << 4;
  const unsigned key = ((unsigned)(l & 7)) << 4;
  const int rowj = (l >> 4) * 4;

  float bsum = 0.0f;
  for (int t = blockIdx.x; t < ntiles; t += 256) {
    int bi = t / nj, bj = t - bi * nj;
    int rm = min(256, M - bi * 256);
    int rn = min(256, NL - bj * 256);
    bool full = (rm == 256) && (rn == 256);

    unsigned aoff[4], boff[4];
#pragma unroll
    for (int j = 0; j < 4; ++j) {
      int rr = rsub + 64 * j;
      int ga = idxNL[bi * 256 + min(rr, rm - 1)];
      int gb = idxL [bj * 256 + min(rr, rn - 1)];
      aoff[j] = (unsigned)ga * 512u + pe;
      boff[j] = (unsigned)gb * 512u + pe;
    }

    auto stage = [&](int buf, int ch) {
      char* dA = &lds[buf][(w << 10)];
      char* dB = &lds[buf][32768 + (w << 10)];
      unsigned cbo = (unsigned)(ch << 7);
#pragma unroll
      for (int j = 0; j < 4; ++j)
        gl_lds16(xnb + (size_t)(aoff[j] + cbo), dA + (j << 13));
#pragma unroll
      for (int j = 0; j < 4; ++j)
        gl_lds16(xnb + (size_t)(boff[j] + cbo), dB + (j << 13));
    };

    f32x4 acc[8][4];
#pragma unroll
    for (int m = 0; m < 8; ++m)
#pragma unroll
      for (int n = 0; n < 4; ++n)
        acc[m][n] = (f32x4){0.f, 0.f, 0.f, 0.f};

    auto compute = [&](int buf) {
      const char* bA = lds[buf];
      const char* bB = lds[buf] + 32768;
#pragma unroll
      for (int ks = 0; ks < 2; ++ks) {
        const unsigned q = (unsigned)(ks * 64) + q16;
        bf16x8 af[8], bfr[4];
#pragma unroll
        for (int m = 0; m < 8; ++m)
          af[m] = *(const bf16x8*)(bA + (wr + m * 16 + l15) * 128 + (q ^ key));
#pragma unroll
        for (int n = 0; n < 4; ++n)
          bfr[n] = *(const bf16x8*)(bB + (wc + n * 16 + l15) * 128 + (q ^ key));
#pragma unroll
        for (int m = 0; m < 8; ++m)
#pragma unroll
          for (int n = 0; n < 4; ++n)
            acc[m][n] = __builtin_amdgcn_mfma_f32_16x16x32_bf16(af[m], bfr[n], acc[m][n], 0, 0, 0);
      }
    };

    __syncthreads();   // protect LDS reuse across tiles
    stage(0, 0); stage(1, 1);
    asm volatile("s_waitcnt vmcnt(8)" ::: "memory");
    __builtin_amdgcn_s_barrier();
    compute(0);
    __builtin_amdgcn_s_barrier();
    stage(0, 2);
    asm volatile("s_waitcnt vmcnt(8)" ::: "memory");
    __builtin_amdgcn_s_barrier();
    compute(1);
    __builtin_amdgcn_s_barrier();
    stage(1, 3);
    asm volatile("s_waitcnt vmcnt(8)" ::: "memory");
    __builtin_amdgcn_s_barrier();
    compute(0);
    __builtin_amdgcn_s_barrier();
    asm volatile("s_waitcnt vmcnt(0)" ::: "memory");
    __builtin_amdgcn_s_barrier();
    compute(1);

    if (full) {
#pragma unroll
      for (int m = 0; m < 8; ++m)
#pragma unroll
        for (int n = 0; n < 4; ++n)
#pragma unroll
          for (int j = 0; j < 4; ++j)
            bsum += fmaxf(acc[m][n][j] - 0.5f, 0.0f);
    } else {
#pragma unroll
      for (int m = 0; m < 8; ++m) {
#pragma unroll
        for (int j = 0; j < 4; ++j) {
          bool rv = (wr + m * 16 + rowj + j) < rm;
#pragma unroll
          for (int n = 0; n < 4; ++n) {
            bool cv = (wc + n * 16 + l15) < rn;
            float g = fmaxf(acc[m][n][j] - 0.5f, 0.0f);
            bsum += (rv && cv) ? g : 0.0f;
          }
        }
      }
    }
  }

#pragma unroll
  for (int off = 32; off; off >>= 1) bsum += __shfl_xor(bsum, off);
  if (l == 0) wred[w] = bsum;
  __syncthreads();
  if (tid == 0) {
    float s = 0.0f;
#pragma unroll
    for (int i = 0; i < 8; ++i) s += wred[i];
    partial[blockIdx.x] = s;
  }
}

// ---- final: closed-form same-class term + diff partials -> out ----
__global__ __launch_bounds__(256) void k_final(const float* __restrict__ cs,
                                               const int* __restrict__ cnt,
                                               const float* __restrict__ partial2,
                                               float* __restrict__ out) {
  __shared__ float sred[4];
  __shared__ float acc8[8];
  const int tid = threadIdx.x, wv = tid >> 6, lane = tid & 63;

  float m0 = 0, m1 = 0, m2 = 0, m3 = 0;
  for (int b = 0; b < 128; ++b) {
    const float* p = cs + b * 1024;
    m0 += p[tid]; m1 += p[256 + tid]; m2 += p[512 + tid]; m3 += p[768 + tid];
  }
  float T = m0 + m1 + m2 + m3;
  float vals[8];
  vals[0] = m0 * m0; vals[1] = m1 * m1; vals[2] = m2 * m2; vals[3] = m3 * m3;
  vals[4] = (T - m0) * (T - m0); vals[5] = (T - m1) * (T - m1);
  vals[6] = (T - m2) * (T - m2); vals[7] = (T - m3) * (T - m3);
#pragma unroll
  for (int v = 0; v < 8; ++v) {
    float s = vals[v];
#pragma unroll
    for (int off = 32; off; off >>= 1) s += __shfl_xor(s, off);
    if (lane == 0) sred[wv] = s;
    __syncthreads();
    if (tid == 0) acc8[v] = sred[0] + sred[1] + sred[2] + sred[3];
    __syncthreads();
  }
  float s = partial2[tid];
#pragma unroll
  for (int off = 32; off; off >>= 1) s += __shfl_xor(s, off);
  if (lane == 0) sred[wv] = s;
  __syncthreads();
  if (tid == 0) {
    double dsum = (double)sred[0] + sred[1] + sred[2] + sred[3];
    double D = (double)NROWS;   // sum of |unit vector|^2
    double same = 0.0;
#pragma unroll
    for (int i = 0; i < 4; ++i) {
      int k = cnt[i];
      if (k > 0) {
        double Pi = 0.5 * (double)k * (double)(k - 1)
                  + 0.5 * (double)(NROWS - k) * (double)(NROWS - k - 1);
        double Si = 0.5 * ((double)acc8[i] + (double)acc8[4 + i] - D);
        same += (Pi - Si) / (double)k;
      }
    }
    out[0] = (float)((same + dsum) / (double)NROWS);
  }
}

extern "C" void kernel_launch(void* const* d_in, const int* in_sizes, int n_in,
                              void* d_out, int out_size, void* d_ws, size_t ws_size,
                              hipStream_t stream) {
  (void)in_sizes; (void)n_in; (void)out_size; (void)ws_size;
  const float* x  = (const float*)d_in[0];
  const int* tgt  = (const int*)d_in[1];
  float* out      = (float*)d_out;
  char* ws        = (char*)d_ws;

  int* cnt        = (int*)(ws + CNT_OFF);
  int* ctr        = (int*)(ws + CTR_OFF);
  float* partial2 = (float*)(ws + P2_OFF);
  int* h          = (int*)(ws + H_OFF);
  unsigned short* idxNL = (unsigned short*)(ws + IDXNL_OFF);
  unsigned short* idxL  = (unsigned short*)(ws + IDXL_OFF);
  float* cs       = (float*)(ws + CS_OFF);
  unsigned short* xn = (unsigned short*)(ws + XN_OFF);

  k_normcs<<<128, 1024, 0, stream>>>(x, tgt, xn, h, cs);
  k_part<<<32, 256, 0, stream>>>(tgt, h, cnt, ctr, idxNL, idxL);
  k_main<<<256, 512, 0, stream>>>((const char*)xn, idxNL, idxL, ctr, partial2);
  k_final<<<1, 256, 0, stream>>>(cs, cnt, partial2, out);
}

// Round 7
// 54.011 us; speedup vs baseline: 1.5079x; 1.2911x over previous
//
#include <hip/hip_runtime.h>

#define NROWS 8192
// ws layout (bytes) — nothing requires pre-zeroed workspace
#define CNT_OFF   0         // int cnt[4]      (k_part)
#define CTR_OFF   16        // int ctr[2]      (k_part)
#define P2_OFF    64        // float partial2[512] (k_main)
#define H_OFF     4096      // int h[128][4]   (k_normcs)
#define IDXNL_OFF 8192      // u16[8192]
#define IDXL_OFF  24576     // u16[8192]
#define CS_OFF    65536     // float cs[128][4][256] (512 KB)
#define XN_OFF    1048576   // bf16 xn[8192][256] (4 MB)

typedef __bf16 bf16x8 __attribute__((ext_vector_type(8)));
typedef float  f32x4  __attribute__((ext_vector_type(4)));

__device__ __forceinline__ unsigned short f2bf(float f) {
  unsigned int u = __float_as_uint(f);
  u += 0x7fffu + ((u >> 16) & 1u);
  return (unsigned short)(u >> 16);
}

__device__ __forceinline__ void gl_lds16(const void* g, void* l) {
  __builtin_amdgcn_global_load_lds(
      (const __attribute__((address_space(1))) unsigned int*)g,
      (__attribute__((address_space(3))) unsigned int*)l, 16, 0, 0);
}

// ---- normalize + bf16 + per-block class hist + class column-sums (no fat atomics) ----
// 128 blocks x 1024 threads, 64 rows/block. Phase 1: wave w normalizes rows w*4..+3,
// writes bf16 xn + f32 rows to LDS. Phase 2: thread (c=tid>>8, col=tid&255) does a
// predicated column sum over 64 rows (uniform row per iter -> 2-way banks, free).
__global__ __launch_bounds__(1024) void k_normcs(const float* __restrict__ x,
                                                 const int* __restrict__ tgt,
                                                 unsigned short* __restrict__ xn,
                                                 int* __restrict__ h,
                                                 float* __restrict__ cs) {
  __shared__ float lx[64][256];    // 64 KB
  __shared__ int lt[64];
  __shared__ int lh[4];
  const int tid = threadIdx.x, w = tid >> 6, lane = tid & 63;
  const int b = blockIdx.x;
  if (tid < 4) lh[tid] = 0;
  if (tid < 64) lt[tid] = tgt[b * 64 + tid];
#pragma unroll
  for (int i = 0; i < 4; ++i) {
    int r = w * 4 + i;
    int row = b * 64 + r;
    float4 v = reinterpret_cast<const float4*>(x)[row * 64 + lane];
    float ss = v.x * v.x + v.y * v.y + v.z * v.z + v.w * v.w;
#pragma unroll
    for (int off = 32; off; off >>= 1) ss += __shfl_xor(ss, off);
    float iv = 1.0f / fmaxf(sqrtf(ss), 1e-8f);
    float4 nv = make_float4(v.x * iv, v.y * iv, v.z * iv, v.w * iv);
    ushort4 o;
    o.x = f2bf(nv.x); o.y = f2bf(nv.y); o.z = f2bf(nv.z); o.w = f2bf(nv.w);
    reinterpret_cast<ushort4*>(xn)[row * 64 + lane] = o;
    *reinterpret_cast<float4*>(&lx[r][lane * 4]) = nv;
  }
  __syncthreads();
  if (tid < 64) atomicAdd(&lh[lt[tid]], 1);
  {
    const int c = tid >> 8, col = tid & 255;
    float m = 0.0f;
#pragma unroll 8
    for (int r = 0; r < 64; ++r)
      m += (lt[r] == c) ? lx[r][col] : 0.0f;
    cs[b * 1024 + tid] = m;
  }
  __syncthreads();
  if (tid < 4) h[b * 4 + tid] = lh[tid];
}

// ---- partition rows into (non-L, L) lists; no global atomics ----
__global__ __launch_bounds__(256) void k_part(const int* __restrict__ tgt,
                                              const int* __restrict__ h,
                                              int* __restrict__ cnt,
                                              int* __restrict__ ctr,
                                              unsigned short* __restrict__ idxNL,
                                              unsigned short* __restrict__ idxL) {
  __shared__ int lcnt[4], lnb, lwc[4];
  const int tid = threadIdx.x, w = tid >> 6, lane = tid & 63;
  if (tid < 4) lcnt[tid] = 0;
  if (tid == 0) lnb = 0;
  __syncthreads();
  if (tid < 128) {
    int4 hv = ((const int4*)h)[tid];
    atomicAdd(&lcnt[0], hv.x); atomicAdd(&lcnt[1], hv.y);
    atomicAdd(&lcnt[2], hv.z); atomicAdd(&lcnt[3], hv.w);
  }
  __syncthreads();
  int L = 0;
#pragma unroll
  for (int i = 0; i < 4; ++i) if (lcnt[i] > 0) L = i;
  if (tid < 4 * blockIdx.x) atomicAdd(&lnb, h[tid * 4 + L]);
  int r = blockIdx.x * 256 + tid;
  bool isL = (tgt[r] == L);
  unsigned long long mk = __ballot(isL);
  int nl = __popcll(mk);
  if (lane == 0) lwc[w] = nl;
  __syncthreads();
  int baseL = lnb, baseN = blockIdx.x * 256 - lnb;
  for (int w2 = 0; w2 < w; ++w2) { baseL += lwc[w2]; baseN += 64 - lwc[w2]; }
  int pos = __popcll(mk & ((1ull << lane) - 1ull));
  if (isL) idxL[baseL + pos] = (unsigned short)r;
  else     idxNL[baseN + (lane - pos)] = (unsigned short)r;
  if (blockIdx.x == 0 && tid < 4) cnt[tid] = lcnt[tid];
  if (blockIdx.x == 0 && tid == 0) { ctr[1] = lcnt[L]; ctr[0] = NROWS - lcnt[L]; }
}

// ---- rectangle GEMM-reduce: sum relu(c-0.5) over (non-L) x (L) ----
// 128^2 tiles, 256 thr (2x2 waves of 64x64), 4 BK=64 chunks, 2 bufs (64KB -> 2 blocks/CU),
// counted vmcnt, persistent grid-stride over runtime ntiles.
__global__ __launch_bounds__(256, 2) void k_main(const char* __restrict__ xnb,
                                                 const unsigned short* __restrict__ idxNL,
                                                 const unsigned short* __restrict__ idxL,
                                                 const int* __restrict__ ctr,
                                                 float* __restrict__ partial) {
  __shared__ char lds[2][32768];     // [buf][A 16KB | B 16KB]
  __shared__ float wred[4];

  const int tid = threadIdx.x;
  const int w = tid >> 6, l = tid & 63;
  const int M = ctr[0], NL = ctr[1];
  const int ni = (M + 127) >> 7, nj = (NL + 127) >> 7;
  const int ntiles = ni * nj;

  // staging geometry: inst (j,w) covers rows (j*4+w)*8..+8; lane: row +(l>>3), slot l&7
  const int rloc = (l >> 3);                       // row-within-8, == row&7
  const unsigned pe = ((unsigned)((l & 7) ^ rloc)) << 4;   // swizzled 16B k-slot
  const int wr = (w >> 1) * 64, wc = (w & 1) * 64;
  const int l15 = l & 15;
  const unsigned q16 = ((unsigned)(l >> 4)) << 4;
  const unsigned key = ((unsigned)(l & 7)) << 4;
  const int rowj = (l >> 4) * 4;

  float bsum = 0.0f;
  for (int t = blockIdx.x; t < ntiles; t += gridDim.x) {
    int bi = t / nj, bj = t - bi * nj;
    int rm = min(128, M - bi * 128);
    int rn = min(128, NL - bj * 128);
    bool full = (rm == 128) && (rn == 128);

    unsigned aoff[4], boff[4];
#pragma unroll
    for (int j = 0; j < 4; ++j) {
      int row = (j * 4 + w) * 8 + rloc;
      int ga = idxNL[bi * 128 + min(row, rm - 1)];
      int gb = idxL [bj * 128 + min(row, rn - 1)];
      aoff[j] = (unsigned)ga * 512u + pe;
      boff[j] = (unsigned)gb * 512u + pe;
    }

    auto stage = [&](int buf, int ch) {
      unsigned cbo = (unsigned)(ch << 7);
#pragma unroll
      for (int j = 0; j < 4; ++j)
        gl_lds16(xnb + (size_t)(aoff[j] + cbo), &lds[buf][(j * 4 + w) * 1024]);
#pragma unroll
      for (int j = 0; j < 4; ++j)
        gl_lds16(xnb + (size_t)(boff[j] + cbo), &lds[buf][16384 + (j * 4 + w) * 1024]);
    };

    f32x4 acc[4][4];
#pragma unroll
    for (int m = 0; m < 4; ++m)
#pragma unroll
      for (int n = 0; n < 4; ++n)
        acc[m][n] = (f32x4){0.f, 0.f, 0.f, 0.f};

    auto compute = [&](int buf) {
      const char* bA = lds[buf];
      const char* bB = lds[buf] + 16384;
#pragma unroll
      for (int ks = 0; ks < 2; ++ks) {
        const unsigned q = (unsigned)(ks * 64) + q16;
        bf16x8 af[4], bfr[4];
#pragma unroll
        for (int m = 0; m < 4; ++m)
          af[m] = *(const bf16x8*)(bA + (wr + m * 16 + l15) * 128 + (q ^ key));
#pragma unroll
        for (int n = 0; n < 4; ++n)
          bfr[n] = *(const bf16x8*)(bB + (wc + n * 16 + l15) * 128 + (q ^ key));
        __builtin_amdgcn_s_setprio(1);
#pragma unroll
        for (int m = 0; m < 4; ++m)
#pragma unroll
          for (int n = 0; n < 4; ++n)
            acc[m][n] = __builtin_amdgcn_mfma_f32_16x16x32_bf16(af[m], bfr[n], acc[m][n], 0, 0, 0);
        __builtin_amdgcn_s_setprio(0);
      }
    };

    __syncthreads();   // protect LDS reuse across tiles
    stage(0, 0); stage(1, 1);
    asm volatile("s_waitcnt vmcnt(8)" ::: "memory");
    __builtin_amdgcn_s_barrier();
    compute(0);
    __builtin_amdgcn_s_barrier();
    stage(0, 2);
    asm volatile("s_waitcnt vmcnt(8)" ::: "memory");
    __builtin_amdgcn_s_barrier();
    compute(1);
    __builtin_amdgcn_s_barrier();
    stage(1, 3);
    asm volatile("s_waitcnt vmcnt(8)" ::: "memory");
    __builtin_amdgcn_s_barrier();
    compute(0);
    __builtin_amdgcn_s_barrier();
    asm volatile("s_waitcnt vmcnt(0)" ::: "memory");
    __builtin_amdgcn_s_barrier();
    compute(1);

    if (full) {
#pragma unroll
      for (int m = 0; m < 4; ++m)
#pragma unroll
        for (int n = 0; n < 4; ++n)
#pragma unroll
          for (int j = 0; j < 4; ++j)
            bsum += fmaxf(acc[m][n][j] - 0.5f, 0.0f);
    } else {
#pragma unroll
      for (int m = 0; m < 4; ++m) {
#pragma unroll
        for (int j = 0; j < 4; ++j) {
          bool rv = (wr + m * 16 + rowj + j) < rm;
#pragma unroll
          for (int n = 0; n < 4; ++n) {
            bool cv = (wc + n * 16 + l15) < rn;
            float g = fmaxf(acc[m][n][j] - 0.5f, 0.0f);
            bsum += (rv && cv) ? g : 0.0f;
          }
        }
      }
    }
  }

#pragma unroll
  for (int off = 32; off; off >>= 1) bsum += __shfl_xor(bsum, off);
  if (l == 0) wred[w] = bsum;
  __syncthreads();
  if (tid == 0)
    partial[blockIdx.x] = wred[0] + wred[1] + wred[2] + wred[3];
}

// ---- final: closed-form same-class term + diff partials -> out ----
__global__ __launch_bounds__(256) void k_final(const float* __restrict__ cs,
                                               const int* __restrict__ cnt,
                                               const float* __restrict__ partial2,
                                               float* __restrict__ out) {
  __shared__ float sred[4];
  __shared__ float acc8[8];
  const int tid = threadIdx.x, wv = tid >> 6, lane = tid & 63;

  float m0 = 0, m1 = 0, m2 = 0, m3 = 0;
  for (int b = 0; b < 128; ++b) {
    const float* p = cs + b * 1024;
    m0 += p[tid]; m1 += p[256 + tid]; m2 += p[512 + tid]; m3 += p[768 + tid];
  }
  float T = m0 + m1 + m2 + m3;
  float vals[8];
  vals[0] = m0 * m0; vals[1] = m1 * m1; vals[2] = m2 * m2; vals[3] = m3 * m3;
  vals[4] = (T - m0) * (T - m0); vals[5] = (T - m1) * (T - m1);
  vals[6] = (T - m2) * (T - m2); vals[7] = (T - m3) * (T - m3);
#pragma unroll
  for (int v = 0; v < 8; ++v) {
    float s = vals[v];
#pragma unroll
    for (int off = 32; off; off >>= 1) s += __shfl_xor(s, off);
    if (lane == 0) sred[wv] = s;
    __syncthreads();
    if (tid == 0) acc8[v] = sred[0] + sred[1] + sred[2] + sred[3];
    __syncthreads();
  }
  float s = partial2[tid] + partial2[tid + 256];
#pragma unroll
  for (int off = 32; off; off >>= 1) s += __shfl_xor(s, off);
  if (lane == 0) sred[wv] = s;
  __syncthreads();
  if (tid == 0) {
    double dsum = (double)sred[0] + sred[1] + sred[2] + sred[3];
    double D = (double)NROWS;   // sum of |unit vector|^2
    double same = 0.0;
#pragma unroll
    for (int i = 0; i < 4; ++i) {
      int k = cnt[i];
      if (k > 0) {
        double Pi = 0.5 * (double)k * (double)(k - 1)
                  + 0.5 * (double)(NROWS - k) * (double)(NROWS - k - 1);
        double Si = 0.5 * ((double)acc8[i] + (double)acc8[4 + i] - D);
        same += (Pi - Si) / (double)k;
      }
    }
    out[0] = (float)((same + dsum) / (double)NROWS);
  }
}

extern "C" void kernel_launch(void* const* d_in, const int* in_sizes, int n_in,
                              void* d_out, int out_size, void* d_ws, size_t ws_size,
                              hipStream_t stream) {
  (void)in_sizes; (void)n_in; (void)out_size; (void)ws_size;
  const float* x  = (const float*)d_in[0];
  const int* tgt  = (const int*)d_in[1];
  float* out      = (float*)d_out;
  char* ws        = (char*)d_ws;

  int* cnt        = (int*)(ws + CNT_OFF);
  int* ctr        = (int*)(ws + CTR_OFF);
  float* partial2 = (float*)(ws + P2_OFF);
  int* h          = (int*)(ws + H_OFF);
  unsigned short* idxNL = (unsigned short*)(ws + IDXNL_OFF);
  unsigned short* idxL  = (unsigned short*)(ws + IDXL_OFF);
  float* cs       = (float*)(ws + CS_OFF);
  unsigned short* xn = (unsigned short*)(ws + XN_OFF);

  k_normcs<<<128, 1024, 0, stream>>>(x, tgt, xn, h, cs);
  k_part<<<32, 256, 0, stream>>>(tgt, h, cnt, ctr, idxNL, idxL);
  k_main<<<512, 256, 0, stream>>>((const char*)xn, idxNL, idxL, ctr, partial2);
  k_final<<<1, 256, 0, stream>>>(cs, cnt, partial2, out);
}